// Round 2
// baseline (723.790 us; speedup 1.0000x reference)
//
#include <hip/hip_runtime.h>
#include <hip/hip_bf16.h>

// VQVAE forward, MI355X, fp32 encoder path (argmin stability).
// v2: parity-split h1 (stride-1 conv2, aligned b128 LDS reads), d1 never
// materialized (stats-only pass + LDS recompute in decoder), merged prep.
// Pipeline: kP prep | k1 conv1->h1p + stats | k_stats | k3 conv2 + stats |
// k_stats | k5 preq+VQ | k7s d1-stats(+qloss) | k_stats | k9 convT2+tanh.

#define EPSB 1e-5f

__device__ __forceinline__ float wredf(float v){
#pragma unroll
  for (int m = 32; m >= 1; m >>= 1) v += __shfl_xor(v, m, 64);
  return v;
}

// ---------------- kP: weight transposes + P table + TT table + qsum=0 -------
__global__ __launch_bounds__(256) void kP(
    const float* __restrict__ w1, const float* __restrict__ w2,
    const float* __restrict__ dw2, const float* __restrict__ dw1,
    const float* __restrict__ pqw, const float* __restrict__ pqb,
    const float* __restrict__ emb,
    float* __restrict__ wt1, float* __restrict__ wt2,
    float* __restrict__ wt9, float* __restrict__ misc)
{
  const int b = blockIdx.x, t = threadIdx.x;
  const int s = b*256 + t;                       // 0..16383
  { int tap = s >> 6, co = s & 63;               // wt2[tap=ci*16+ky*4+kx][co64]
    int ci = tap >> 4, ky = (tap >> 2) & 3, kx = tap & 3;
    wt2[s] = w2[((co*16 + ci)*4 + ky)*4 + kx]; }
  if (b == 0){
    for (int s2 = t; s2 < 768; s2 += 256){
      int tap = s2 >> 4, co = s2 & 15;           // wt1[tap][co16]
      int ci = tap >> 4, ky = (tap >> 2) & 3, kx = tap & 3;
      wt1[s2] = w1[((co*3 + ci)*4 + ky)*4 + kx];
      int ky9 = s2 / 192, rem = s2 - ky9*192;    // wt9[ky][ci][kx*3+co]
      int ci9 = rem / 12, r12 = rem - ci9*12;
      int kx9 = r12 / 3, co9 = r12 - kx9*3;
      wt9[s2] = dw2[((ci9*3 + co9)*4 + ky9)*4 + kx9];
    }
    if (t < 192){                                // P[i][ci] = postq(emb[i])
      int i = t >> 6, ci = t & 63;
      misc[200 + t] = fmaf(pqw[ci*2], emb[i*2],
                      fmaf(pqw[ci*2 + 1], emb[i*2 + 1], pqb[ci]));
    }
    if (t == 255) misc[192] = 0.f;               // qloss accumulator
    __syncthreads();
    for (int e = t; e < 768; e += 256){          // TT[i][ky][kx][oc]
      int i = e >> 8, rem = e & 255, kykx = rem >> 4, oc = rem & 15;
      int ky = kykx >> 2, kx = kykx & 3;
      float acc = 0.f;
      for (int ci = 0; ci < 64; ci++)
        acc += dw1[((ci*16 + oc)*4 + ky)*4 + kx] * misc[200 + i*64 + ci];
      misc[400 + i*260 + rem] = acc;             // stride 260 (1040B, 16-mult)
    }
  }
}

// ---------------- k1: conv1 3->16 s2 p1 -> parity-split h1p + stats ----------
// h1p[n][co16][yp][xp][128][128]; yp=oy&1, xp=ox&1.
__global__ __launch_bounds__(256) void k1_conv1(
    const float* __restrict__ x, const float* __restrict__ wt1,
    float* __restrict__ h1p, float* __restrict__ part1)
{
  __shared__ __align__(16) float xt[3*6*516];
  __shared__ float red[128];
  const int b = blockIdx.x, t = threadIdx.x;
  const int n = b >> 7, yt = b & 127;
  const int oy0 = yt << 1, iy0 = (oy0 << 1) - 1;
  for (int ci = 0; ci < 3; ci++)
    for (int rr = 0; rr < 6; rr++){
      int iy = iy0 + rr;
      const float* xr = x + (((size_t)(n*3 + ci)) << 18) + ((size_t)(iy & 511) << 9);
      float* dst = &xt[(ci*6 + rr)*516];
      bool yok = (unsigned)iy < 512u;
      for (int c = t; c < 514; c += 256){
        int ix = c - 1;
        dst[c] = (yok && (unsigned)ix < 512u) ? xr[ix] : 0.f;
      }
    }
  __syncthreads();
  const int w = t >> 6, l = t & 63;
  const int oyr = w & 1, xh = w >> 1;
  float acc[2][16];
#pragma unroll
  for (int j = 0; j < 2; j++)
#pragma unroll
    for (int q = 0; q < 16; q++) acc[j][q] = 0.f;

  for (int ci = 0; ci < 3; ci++){
    for (int ky = 0; ky < 4; ky++){
      const float* xrow = &xt[(ci*6 + (oyr << 1) + ky)*516];
      float v[2][4];
#pragma unroll
      for (int j = 0; j < 2; j++){
        int ox = (xh << 7) + (j << 6) + l;
        float2 p0 = *(const float2*)&xrow[2*ox];
        float2 p1 = *(const float2*)&xrow[2*ox + 2];
        v[j][0] = p0.x; v[j][1] = p0.y; v[j][2] = p1.x; v[j][3] = p1.y;
      }
      const float* wb = &wt1[((ci*4 + ky) << 6)];
#pragma unroll
      for (int kx = 0; kx < 4; kx++){
        const float* wp = wb + (kx << 4);        // uniform -> s_load
        float wv[16];
#pragma unroll
        for (int q = 0; q < 16; q++) wv[q] = wp[q];
#pragma unroll
        for (int j = 0; j < 2; j++)
#pragma unroll
          for (int q = 0; q < 16; q++) acc[j][q] = fmaf(v[j][kx], wv[q], acc[j][q]);
      }
    }
  }
  float s[16], ss[16];
#pragma unroll
  for (int q = 0; q < 16; q++){ s[q] = 0.f; ss[q] = 0.f; }
  const int xp = l & 1;
#pragma unroll
  for (int j = 0; j < 2; j++){
    int m = (xh << 6) + (j << 5) + (l >> 1);
#pragma unroll
    for (int q = 0; q < 16; q++){
      float vv = acc[j][q];
      h1p[((((size_t)(n*16 + q) << 1) + oyr) << 15) + ((size_t)xp << 14) + (yt << 7) + m] = vv;
      s[q] += vv; ss[q] += vv*vv;
    }
  }
#pragma unroll
  for (int q = 0; q < 16; q++){ s[q] = wredf(s[q]); ss[q] = wredf(ss[q]); }
  if (l == 0){
#pragma unroll
    for (int q = 0; q < 16; q++){ red[w*32 + q] = s[q]; red[w*32 + 16 + q] = ss[q]; }
  }
  __syncthreads();
  if (t < 32) part1[b*32 + t] = red[t] + red[32+t] + red[64+t] + red[96+t];
}

// ---------------- reduce partials -> scale/shift (BN) ------------------------
__global__ __launch_bounds__(256) void k_stats(
    const float* __restrict__ part, int nslots, int slotstride, int grouped,
    const float* __restrict__ g, const float* __restrict__ be,
    float* __restrict__ scale, float* __restrict__ shift, float Ninv)
{
  const int c = blockIdx.x, t = threadIdx.x;
  const int off = grouped ? ((c >> 4) << 5) : 0;
  const int ci = grouped ? (c & 15) : c;
  float S = 0.f, SS = 0.f;
  for (int q = t; q < nslots; q += 256){
    const float* pp = &part[(size_t)q * slotstride + off];
    S += pp[ci]; SS += pp[16 + ci];
  }
  S = wredf(S); SS = wredf(SS);
  __shared__ float sb[8];
  if ((t & 63) == 0){ sb[t >> 6] = S; sb[4 + (t >> 6)] = SS; }
  __syncthreads();
  if (t == 0){
    float Sv = sb[0]+sb[1]+sb[2]+sb[3], SSv = sb[4]+sb[5]+sb[6]+sb[7];
    float m = Sv * Ninv;
    float var = SSv * Ninv - m*m;
    float sc = g[c] * rsqrtf(var + EPSB);
    scale[c] = sc;
    shift[c] = be[c] - m * sc;
  }
}

// ---------------- k3: conv2 16->64 s2 p1, parity-plane stride-1 --------------
// LDS a1: [ci4][yp2][r3][xp2][136], m at col m+4 (cols 0..3 zero halo).
__global__ __launch_bounds__(256) void k3_conv2(
    const float* __restrict__ h1p, const float* __restrict__ wt2,
    const float* __restrict__ misc, float* __restrict__ h2,
    float* __restrict__ part2)
{
  __shared__ __align__(16) float a1[6528];
  __shared__ float red[128];
  const int b = blockIdx.x, t = threadIdx.x;
  const int n = b >> 6, yt = b & 63;
  const int oy0 = yt << 1;
  const int cg = __builtin_amdgcn_readfirstlane(t >> 6);
  const int l = t & 63, oyr = l >> 5, lx = l & 31;
  float acc[4][16];
#pragma unroll
  for (int e = 0; e < 4; e++)
#pragma unroll
    for (int q = 0; q < 16; q++) acc[e][q] = 0.f;

  for (int cc = 0; cc < 4; cc++){
    __syncthreads();
    // stage 4 ci x {yp0 rows oy0..oy0+2 ; yp1 rows oy0-1..oy0+1} x 2 xp x 136
    for (int ci = 0; ci < 4; ci++){
      int gci = (cc << 2) + ci;
      float sc = misc[gci], sh = misc[16 + gci];
      const float* hbase = h1p + (((size_t)(n*16 + gci)) << 16);
#pragma unroll
      for (int yp = 0; yp < 2; yp++)
        for (int r = 0; r < 3; r++){
          int m_y = yp ? (oy0 - 1 + r) : (oy0 + r);
          bool yok = (unsigned)m_y < 128u;
          const float* src = hbase + ((size_t)yp << 15) + ((m_y & 127) << 7);
          float* dst = &a1[(((ci << 1) + yp)*3 + r) * 272];
          for (int s = t; s < 272; s += 256){
            int xp = (s >= 136) ? 1 : 0;
            int col = s - (xp ? 136 : 0);
            int m = col - 4;
            float v = 0.f;
            if (yok && (unsigned)m < 128u)
              v = fmaxf(fmaf(src[(xp << 14) + m], sc, sh), 0.f);
            dst[s] = v;
          }
        }
    }
    __syncthreads();
    for (int cl = 0; cl < 4; cl++){
#pragma unroll
      for (int ky = 0; ky < 4; ky++){
        const int yp = 1 - (ky & 1);
        const int r  = oyr + (ky >> 1);
        const float* rowp = &a1[(((cl << 1) + yp)*3 + r) * 272];
        const float* r0 = rowp + 4;          // xp0, m=0
        const float* r1 = rowp + 140;        // xp1, m=0
        float4 a0 = *(const float4*)(r0 + (lx << 2));
        float  a4 = r0[(lx << 2) + 4];
        float  b0 = r1[(lx << 2) - 1];
        float4 b1 = *(const float4*)(r1 + (lx << 2));
        float v0[5] = {a0.x, a0.y, a0.z, a0.w, a4};
        float v1[5] = {b0, b1.x, b1.y, b1.z, b1.w};
        const float* wb = &wt2[(size_t)cc*4096 + (((cl << 4) + (ky << 2)) << 6) + (cg << 4)];
#pragma unroll
        for (int kx = 0; kx < 4; kx++){
          const float* wp = wb + (kx << 6);  // uniform -> s_load
          float wv[16];
#pragma unroll
          for (int q = 0; q < 16; q++) wv[q] = wp[q];
          const float* vs = (kx & 1) ? v0 : v1;
          const int voff = kx >> 1;
#pragma unroll
          for (int e = 0; e < 4; e++){
            float va = vs[e + voff];
#pragma unroll
            for (int q = 0; q < 16; q++) acc[e][q] = fmaf(va, wv[q], acc[e][q]);
          }
        }
      }
    }
  }
  const int oy = oy0 + oyr;
  float s[16], ss[16];
#pragma unroll
  for (int q = 0; q < 16; q++){ s[q] = 0.f; ss[q] = 0.f; }
#pragma unroll
  for (int e = 0; e < 4; e++)
#pragma unroll
    for (int q = 0; q < 16; q++){ float v = acc[e][q]; s[q] += v; ss[q] += v*v; }
#pragma unroll
  for (int q = 0; q < 16; q++){
    float4 o = make_float4(acc[0][q], acc[1][q], acc[2][q], acc[3][q]);
    *(float4*)&h2[(((size_t)(n*64) + (cg << 4) + q) << 14) + (oy << 7) + (lx << 2)] = o;
  }
#pragma unroll
  for (int q = 0; q < 16; q++){ s[q] = wredf(s[q]); ss[q] = wredf(ss[q]); }
  if (l == 0){
#pragma unroll
    for (int q = 0; q < 16; q++){ red[cg*32 + q] = s[q]; red[cg*32 + 16 + q] = ss[q]; }
  }
  __syncthreads();
  if (t < 128) part2[b*128 + t] = red[t];
}

// ---------------- k5: preq(bn2+relu fused) + VQ argmin + qloss + idx ---------
__global__ __launch_bounds__(256) void k5_vq(
    const float* __restrict__ h2, const float* __restrict__ misc,
    const float* __restrict__ pw, const float* __restrict__ pb,
    const float* __restrict__ emb, unsigned char* __restrict__ idxb,
    float* __restrict__ qsum)
{
  __shared__ float s2[64], t2[64], w0s[64], w1s[64];
  __shared__ float eb[4];
  const int t = threadIdx.x;
  if (t < 64){ s2[t] = misc[32 + t]; t2[t] = misc[96 + t]; w0s[t] = pw[t]; w1s[t] = pw[64 + t]; }
  __syncthreads();
  const int p = blockIdx.x * 256 + t;
  const int n = p >> 14, pos = p & 16383;
  const float* hp = h2 + ((size_t)n << 20) + pos;
  float q0 = pb[0], q1 = pb[1];
  for (int c = 0; c < 64; c++){
    float v = fmaxf(fmaf(hp[(size_t)c << 14], s2[c], t2[c]), 0.f);
    q0 = fmaf(v, w0s[c], q0);
    q1 = fmaf(v, w1s[c], q1);
  }
  float dx0 = q0-emb[0], dy0 = q1-emb[1];
  float dx1 = q0-emb[2], dy1 = q1-emb[3];
  float dx2 = q0-emb[4], dy2 = q1-emb[5];
  float d0 = dx0*dx0+dy0*dy0, d1 = dx1*dx1+dy1*dy1, d2 = dx2*dx2+dy2*dy2;
  int bi = 0; float db = d0;
  if (d1 < db){ db = d1; bi = 1; }
  if (d2 < db){ db = d2; bi = 2; }
  idxb[p] = (unsigned char)bi;
  float e = wredf(db);
  if ((t & 63) == 0) eb[t >> 6] = e;
  __syncthreads();
  if (t == 0) atomicAdd(qsum, eb[0]+eb[1]+eb[2]+eb[3]);
}

// d1raw at (iy,ix): sum of <=4 TT entries via idx map (convT1 collapsed)
__device__ __forceinline__ void d1_accum(const unsigned char* __restrict__ ib,
    int iy, int ix, const float* __restrict__ tt, float* __restrict__ d)
{
  const int py = (iy + 1) & 1, px = (ix + 1) & 1;
#pragma unroll
  for (int kyi = 0; kyi < 2; kyi++){
    int ky = py + 2*kyi, jy = (iy + 1 - ky) >> 1;
    if ((unsigned)jy < 128u){
#pragma unroll
      for (int kxi = 0; kxi < 2; kxi++){
        int kx = px + 2*kxi, jx = (ix + 1 - kx) >> 1;
        if ((unsigned)jx < 128u){
          const float* tb = &tt[(int)ib[(jy << 7) + jx]*260 + (((ky << 2) + kx) << 4)];
#pragma unroll
          for (int q = 0; q < 16; q++) d[q] += tb[q];
        }
      }
    }
  }
}

// ---------------- k7s: d1 batch-stats only (no materialization) + qloss ------
__global__ __launch_bounds__(256) void k7s(
    const unsigned char* __restrict__ idxb, const float* __restrict__ misc,
    float* __restrict__ partd, float* __restrict__ qout)
{
  __shared__ __align__(16) float tt[780];
  __shared__ float red[128];
  const int b = blockIdx.x, t = threadIdx.x;
  for (int s = t; s < 780; s += 256) tt[s] = misc[400 + s];
  __syncthreads();
  if (b == 0 && t == 0) qout[0] = 1.2f * misc[192] * (1.0f/1048576.0f);
  float s[16], ss[16];
#pragma unroll
  for (int q = 0; q < 16; q++){ s[q] = 0.f; ss[q] = 0.f; }
  for (int k = 0; k < 8; k++){
    int p = (b << 11) + (k << 8) + t;
    int n = p >> 16, rem = p & 65535, iy = rem >> 8, ix = rem & 255;
    const unsigned char* ib = idxb + ((size_t)n << 14);
    float d[16];
#pragma unroll
    for (int q = 0; q < 16; q++) d[q] = 0.f;
    d1_accum(ib, iy, ix, tt, d);
#pragma unroll
    for (int q = 0; q < 16; q++){ s[q] += d[q]; ss[q] += d[q]*d[q]; }
  }
#pragma unroll
  for (int q = 0; q < 16; q++){ s[q] = wredf(s[q]); ss[q] = wredf(ss[q]); }
  const int w = t >> 6, l = t & 63;
  if (l == 0){
#pragma unroll
    for (int q = 0; q < 16; q++){ red[w*32 + q] = s[q]; red[w*32 + 16 + q] = ss[q]; }
  }
  __syncthreads();
  if (t < 32) partd[b*32 + t] = red[t] + red[32+t] + red[64+t] + red[96+t];
}

// ---------------- k9: convT2 from LDS-recomputed bn_d+relu d1, + tanh --------
__global__ __launch_bounds__(256) void k9_dec(
    const unsigned char* __restrict__ idxb, const float* __restrict__ misc,
    const float* __restrict__ wt9, const float* __restrict__ db2,
    float* __restrict__ out)
{
  __shared__ __align__(16) float a[4*16*132];   // [iyr][ci][132], col = ixl+1
  __shared__ __align__(16) float tt[780];
  __shared__ float sd[16], shs[16];
  const int b = blockIdx.x, t = threadIdx.x;
  const int n = b >> 8, r8 = b & 255, G = r8 >> 1, xh = r8 & 1;
  const int M0 = xh << 7;
  for (int s = t; s < 780; s += 256) tt[s] = misc[400 + s];
  if (t < 16){ sd[t] = misc[160 + t]; shs[t] = misc[176 + t]; }
  __syncthreads();
  const unsigned char* ib = idxb + ((size_t)n << 14);
  // stage: iyr 0..3 (iy = 2G-1+iyr), cols 0..129 (ix = M0+col-1)
#pragma unroll
  for (int pass = 0; pass < 2; pass++){
    int s = t + (pass << 8);
    int iyr = s >> 7, col = s & 127;
    int iy = (G << 1) - 1 + iyr, ix = M0 + col - 1;
    bool inb = ((unsigned)iy < 256u) && ((unsigned)ix < 256u);
    float d[16];
#pragma unroll
    for (int q = 0; q < 16; q++) d[q] = 0.f;
    if (inb) d1_accum(ib, iy, ix, tt, d);
#pragma unroll
    for (int q = 0; q < 16; q++)
      a[(iyr*16 + q)*132 + col] = inb ? fmaxf(fmaf(d[q], sd[q], shs[q]), 0.f) : 0.f;
  }
  if (t < 8){
    int iyr = t >> 1, col = 128 + (t & 1);
    int iy = (G << 1) - 1 + iyr, ix = M0 + col - 1;
    bool inb = ((unsigned)iy < 256u) && ((unsigned)ix < 256u);
    float d[16];
#pragma unroll
    for (int q = 0; q < 16; q++) d[q] = 0.f;
    if (inb) d1_accum(ib, iy, ix, tt, d);
#pragma unroll
    for (int q = 0; q < 16; q++)
      a[(iyr*16 + q)*132 + col] = inb ? fmaxf(fmaf(d[q], sd[q], shs[q]), 0.f) : 0.f;
  }
  __syncthreads();
  const int rowq = t >> 6, u = t & 63;
  const int oy2 = (G << 2) + rowq;
  const int py = (oy2 + 1) & 1;
  float acc[2][2][3];
#pragma unroll
  for (int p2 = 0; p2 < 2; p2++)
#pragma unroll
    for (int e = 0; e < 2; e++)
#pragma unroll
      for (int c = 0; c < 3; c++) acc[p2][e][c] = 0.f;

#pragma unroll
  for (int kyi = 0; kyi < 2; kyi++){
    const int ky = py + (kyi << 1);
    const int iy = (oy2 + 1 - ky) >> 1;
    if ((unsigned)iy < 256u){
      const int iyr = iy - ((G << 1) - 1);
      for (int ci = 0; ci < 16; ci++){
        const float* wp = &wt9[(ky*16 + ci)*12];   // uniform -> s_load
        float w[12];
#pragma unroll
        for (int k = 0; k < 12; k++) w[k] = wp[k];
        const float* ar = &a[(iyr*16 + ci)*132];
        float2 c0 = *(const float2*)&ar[2*u];
        float2 c1 = *(const float2*)&ar[2*u + 2];
        float v[4] = {c0.x, c0.y, c1.x, c1.y};
#pragma unroll
        for (int e = 0; e < 2; e++){
          float vmm = v[e], v0m = v[e+1], vp1 = v[e+2];
          acc[1][e][0] = fmaf(vp1, w[0], acc[1][e][0]);
          acc[1][e][1] = fmaf(vp1, w[1], acc[1][e][1]);
          acc[1][e][2] = fmaf(vp1, w[2], acc[1][e][2]);
          acc[0][e][0] = fmaf(v0m, w[3], acc[0][e][0]);
          acc[0][e][1] = fmaf(v0m, w[4], acc[0][e][1]);
          acc[0][e][2] = fmaf(v0m, w[5], acc[0][e][2]);
          acc[1][e][0] = fmaf(v0m, w[6], acc[1][e][0]);
          acc[1][e][1] = fmaf(v0m, w[7], acc[1][e][1]);
          acc[1][e][2] = fmaf(v0m, w[8], acc[1][e][2]);
          acc[0][e][0] = fmaf(vmm, w[9], acc[0][e][0]);
          acc[0][e][1] = fmaf(vmm, w[10], acc[0][e][1]);
          acc[0][e][2] = fmaf(vmm, w[11], acc[0][e][2]);
        }
      }
    }
  }
  const float bb[3] = {db2[0], db2[1], db2[2]};
#pragma unroll
  for (int co = 0; co < 3; co++){
    float4 o = make_float4(tanhf(acc[0][0][co] + bb[co]), tanhf(acc[1][0][co] + bb[co]),
                           tanhf(acc[0][1][co] + bb[co]), tanhf(acc[1][1][co] + bb[co]));
    *(float4*)&out[((size_t)(n*3 + co) << 18) + ((size_t)oy2 << 9) + (M0 << 1) + (u << 2)] = o;
  }
}

// ---------------------------------------------------------------------------
extern "C" void kernel_launch(void* const* d_in, const int* in_sizes, int n_in,
                              void* d_out, int out_size, void* d_ws, size_t ws_size,
                              hipStream_t stream)
{
  (void)in_sizes; (void)n_in; (void)out_size;
  const float* x       = (const float*)d_in[0];
  const float* enc_w1  = (const float*)d_in[1];
  const float* enc_g1  = (const float*)d_in[3];
  const float* enc_be1 = (const float*)d_in[4];
  const float* enc_w2  = (const float*)d_in[5];
  const float* enc_g2  = (const float*)d_in[7];
  const float* enc_be2 = (const float*)d_in[8];
  const float* preq_w  = (const float*)d_in[9];
  const float* preq_b  = (const float*)d_in[10];
  const float* emb     = (const float*)d_in[11];
  const float* postq_w = (const float*)d_in[12];
  const float* postq_b = (const float*)d_in[13];
  const float* dec_w1  = (const float*)d_in[14];
  const float* dec_g1  = (const float*)d_in[16];
  const float* dec_be1 = (const float*)d_in[17];
  const float* dec_w2  = (const float*)d_in[18];
  const float* dec_b2  = (const float*)d_in[19];
  float* out = (float*)d_out;
  char*  ws  = (char*)d_ws;

  float* h1p = (float*)ws;                         // 134217728 B
  float* h2  = (float*)(ws + 134217728);           // 134217728 B
  size_t ebase = (ws_size - 4194304) & ~(size_t)255;
  unsigned char* idxb = (unsigned char*)(ws + ebase);            // 524288 B
  float* part1 = (float*)(ws + ebase + 524288);                  // 512 KB
  float* part2 = (float*)(ws + ebase + 1572864);                 // 1 MB
  float* partd = (float*)(ws + ebase + 2621440);                 // 128 KB
  float* misc  = (float*)(ws + ebase + 3670016);                 // 2048 f
  float* wt1   = (float*)(ws + ebase + 3678208);                 // 768 f
  float* wt2   = (float*)(ws + ebase + 3681280);                 // 16384 f
  float* wt9   = (float*)(ws + ebase + 3746816);                 // 768 f

  kP<<<64, 256, 0, stream>>>(enc_w1, enc_w2, dec_w2, dec_w1,
                             postq_w, postq_b, emb, wt1, wt2, wt9, misc);
  k1_conv1<<<4096, 256, 0, stream>>>(x, wt1, h1p, part1);
  k_stats<<<16, 256, 0, stream>>>(part1, 4096, 32, 0, enc_g1, enc_be1,
                                  misc + 0, misc + 16, 1.f/2097152.f);
  k3_conv2<<<2048, 256, 0, stream>>>(h1p, wt2, misc, h2, part2);
  k_stats<<<64, 256, 0, stream>>>(part2, 2048, 128, 1, enc_g2, enc_be2,
                                  misc + 32, misc + 96, 1.f/524288.f);
  k5_vq<<<2048, 256, 0, stream>>>(h2, misc, preq_w, preq_b, emb, idxb, misc + 192);
  k7s<<<1024, 256, 0, stream>>>(idxb, misc, partd, out + 25165824);
  k_stats<<<16, 256, 0, stream>>>(partd, 1024, 32, 0, dec_g1, dec_be1,
                                  misc + 160, misc + 176, 1.f/2097152.f);
  k9_dec<<<8192, 256, 0, stream>>>(idxb, misc, wt9, dec_b2, out);
}